// Round 2
// baseline (871.983 us; speedup 1.0000x reference)
//
#include <hip/hip_runtime.h>
#include <hip/hip_bf16.h>

// Problem dims (StandardAttention): x[4,96,256,256], heads=3
#define B_  4
#define C_  96
#define H_  256
#define W_  256
#define N_  (H_*W_)      // 65536
#define C3_ 288
#define HEAD_ 3
#define HC_ 32
#define EPS_ 1e-12f

// ---- bf16 helpers (raw ushort storage) -------------------------------------
__device__ __forceinline__ unsigned short f2bf(float f) {
  unsigned u = __float_as_uint(f);
  u += 0x7fffu + ((u >> 16) & 1u);      // round-to-nearest-even
  return (unsigned short)(u >> 16);
}
__device__ __forceinline__ float bf2f(unsigned short h) {
  return __uint_as_float((unsigned)h << 16);
}
__device__ __forceinline__ float bf_lo(unsigned u) { return __uint_as_float(u << 16); }
__device__ __forceinline__ float bf_hi(unsigned u) { return __uint_as_float(u & 0xffff0000u); }
__device__ __forceinline__ unsigned pack_bf(float a, float b) {
  return (unsigned)f2bf(a) | ((unsigned)f2bf(b) << 16);
}

// ---------------- K1: qkv = qkv_w @ x + qkv_b  (1x1 conv, 96 -> 288) --------
__global__ __launch_bounds__(256) void k_pointwise288(
    const float* __restrict__ x, const float* __restrict__ w,
    const float* __restrict__ bias, unsigned short* __restrict__ out) {
  __shared__ float wsh[8 * 96];
  const int tid = threadIdx.x;
  const int b = blockIdx.y;
  const int n = blockIdx.x * 256 + tid;
  const float* xp = x + (size_t)b * C_ * N_ + n;
  float xr[96];
#pragma unroll
  for (int c = 0; c < 96; ++c) xr[c] = xp[(size_t)c * N_];
  for (int ob = 0; ob < 36; ++ob) {
    __syncthreads();
    for (int i = tid; i < 768; i += 256) wsh[i] = w[ob * 768 + i];
    __syncthreads();
    float acc[8];
#pragma unroll
    for (int o = 0; o < 8; ++o) acc[o] = bias[ob * 8 + o];
#pragma unroll
    for (int c = 0; c < 96; ++c) {
      const float xv = xr[c];
#pragma unroll
      for (int o = 0; o < 8; ++o) acc[o] += wsh[o * 96 + c] * xv;
    }
#pragma unroll
    for (int o = 0; o < 8; ++o)
      out[((size_t)b * C3_ + ob * 8 + o) * N_ + n] = f2bf(acc[o]);
  }
}

// ---------------- K2: 3x3 depthwise conv, pad=1, IN-PLACE on bf16 plane -----
// One block per (b,ch) plane. Rolling 10-slot row ring (+1 zero row) in LDS;
// 8 rows per iteration; each thread handles 8 x-positions (16B packed I/O).
__global__ __launch_bounds__(256) void k_dw_inplace(
    unsigned short* a, const float* __restrict__ w9,
    const float* __restrict__ bias) {
  const int bc = blockIdx.x;            // 0..1151
  const int ch = bc % C3_;
  unsigned short* p = a + (size_t)bc * N_;
  const int tid = threadIdx.x;
  const int tr = tid >> 5;              // 0..7
  const int tc = tid & 31;
  const int x0 = tc * 8;
  __shared__ float ring[11][W_];        // slots 0..9: rows (mod 10); slot 10: zeros
  float wv[9];
#pragma unroll
  for (int i = 0; i < 9; ++i) wv[i] = w9[ch * 9 + i];
  const float bv = bias[ch];
  ring[10][tid] = 0.f;
  // preload rows 0..8
  {
    const uint4 u = *reinterpret_cast<const uint4*>(p + (size_t)tr * W_ + x0);
    float* d = &ring[tr][x0];
    d[0] = bf_lo(u.x); d[1] = bf_hi(u.x); d[2] = bf_lo(u.y); d[3] = bf_hi(u.y);
    d[4] = bf_lo(u.z); d[5] = bf_hi(u.z); d[6] = bf_lo(u.w); d[7] = bf_hi(u.w);
    if (tr == 0) {
      const uint4 v = *reinterpret_cast<const uint4*>(p + (size_t)8 * W_ + x0);
      float* e = &ring[8][x0];
      e[0] = bf_lo(v.x); e[1] = bf_hi(v.x); e[2] = bf_lo(v.y); e[3] = bf_hi(v.y);
      e[4] = bf_lo(v.z); e[5] = bf_hi(v.z); e[6] = bf_lo(v.w); e[7] = bf_hi(v.w);
    }
  }
  __syncthreads();
  for (int y = 0; y < 256; y += 8) {
    const int r = y + tr;
    const float* tp = (r - 1 >= 0) ? ring[(r - 1) % 10] : ring[10];
    const float* mp = ring[r % 10];
    const float* bp = (r + 1 < 256) ? ring[(r + 1) % 10] : ring[10];
    float vt[10], vm[10], vb[10];
#pragma unroll
    for (int j = 0; j < 10; ++j) {
      const int xx = x0 - 1 + j;
      const bool in = (unsigned)xx < 256u;
      vt[j] = in ? tp[xx] : 0.f;
      vm[j] = in ? mp[xx] : 0.f;
      vb[j] = in ? bp[xx] : 0.f;
    }
    float o[8];
#pragma unroll
    for (int j = 0; j < 8; ++j)
      o[j] = bv + wv[0] * vt[j] + wv[1] * vt[j + 1] + wv[2] * vt[j + 2]
                + wv[3] * vm[j] + wv[4] * vm[j + 1] + wv[5] * vm[j + 2]
                + wv[6] * vb[j] + wv[7] * vb[j + 1] + wv[8] * vb[j + 2];
    __syncthreads();   // all ring reads done before slots are recycled
    uint4 st;
    st.x = pack_bf(o[0], o[1]); st.y = pack_bf(o[2], o[3]);
    st.z = pack_bf(o[4], o[5]); st.w = pack_bf(o[6], o[7]);
    *reinterpret_cast<uint4*>(p + (size_t)r * W_ + x0) = st;
    const int nr = y + 9 + tr;          // rows y+9..y+16 for next iter
    if (nr < 256) {
      const uint4 u = *reinterpret_cast<const uint4*>(p + (size_t)nr * W_ + x0);
      float* d = &ring[nr % 10][x0];
      d[0] = bf_lo(u.x); d[1] = bf_hi(u.x); d[2] = bf_lo(u.y); d[3] = bf_hi(u.y);
      d[4] = bf_lo(u.z); d[5] = bf_hi(u.z); d[6] = bf_lo(u.w); d[7] = bf_hi(u.w);
    }
    __syncthreads();
  }
}

// ---------------- K3: inverse L2 norms for q,k rows (768 rows of 65536) -----
__global__ __launch_bounds__(256) void k_l2_inv(
    const unsigned short* __restrict__ dw, float* __restrict__ inv) {
  const int r = blockIdx.x;          // 0..767 : b = r/192, c = r%192
  const int b = r / 192, c = r % 192;
  const uint4* pv = reinterpret_cast<const uint4*>(dw + ((size_t)(b * C3_ + c)) * N_);
  float s = 0.f;
  for (int i = threadIdx.x; i < N_ / 8; i += 256) {
    const uint4 u = pv[i];
    float v0 = bf_lo(u.x), v1 = bf_hi(u.x), v2 = bf_lo(u.y), v3 = bf_hi(u.y);
    float v4 = bf_lo(u.z), v5 = bf_hi(u.z), v6 = bf_lo(u.w), v7 = bf_hi(u.w);
    s += v0 * v0 + v1 * v1 + v2 * v2 + v3 * v3 + v4 * v4 + v5 * v5 + v6 * v6 + v7 * v7;
  }
#pragma unroll
  for (int off = 32; off > 0; off >>= 1) s += __shfl_down(s, off, 64);
  __shared__ float red[4];
  if ((threadIdx.x & 63) == 0) red[threadIdx.x >> 6] = s;
  __syncthreads();
  if (threadIdx.x == 0) {
    float t = red[0] + red[1] + red[2] + red[3];
    inv[r] = 1.0f / fmaxf(sqrtf(t), EPS_);
  }
}

__global__ __launch_bounds__(256) void k_zero(float* __restrict__ p, int n) {
  const int i = blockIdx.x * 256 + threadIdx.x;
  if (i < n) p[i] = 0.f;
}

// ---------------- K4: attn_raw[b,h,i,j] += sum_n q[i,n]*k[j,n]  (split-K) ---
#define TSP_ 129   // 128 + 1 pad
__global__ __launch_bounds__(256) void k_attn_partial(
    const unsigned short* __restrict__ dw, float* __restrict__ attn_raw) {
  __shared__ float qs[32 * TSP_];
  __shared__ float ks[32 * TSP_];
  const int tid = threadIdx.x;
  const int h = blockIdx.y, b = blockIdx.z;
  const unsigned short* qp = dw + ((size_t)(b * C3_ + h * HC_)) * N_;
  const unsigned short* kp = dw + ((size_t)(b * C3_ + C_ + h * HC_)) * N_;
  const int n0 = blockIdx.x * 4096;
  const int i0 = (tid >> 4) << 1, j0 = (tid & 15) << 1;
  float a00 = 0.f, a01 = 0.f, a10 = 0.f, a11 = 0.f;
  for (int s = 0; s < 4096; s += 128) {
    __syncthreads();
#pragma unroll
    for (int l = 0; l < 2; ++l) {
      const int idx = tid + l * 256;       // 0..511
      const int c = idx >> 4;              // 0..31
      const int t0 = (idx & 15) * 8;       // 0..120
      const uint4 uq = *reinterpret_cast<const uint4*>(qp + (size_t)c * N_ + n0 + s + t0);
      float* qd = &qs[c * TSP_ + t0];
      qd[0] = bf_lo(uq.x); qd[1] = bf_hi(uq.x); qd[2] = bf_lo(uq.y); qd[3] = bf_hi(uq.y);
      qd[4] = bf_lo(uq.z); qd[5] = bf_hi(uq.z); qd[6] = bf_lo(uq.w); qd[7] = bf_hi(uq.w);
      const uint4 uk = *reinterpret_cast<const uint4*>(kp + (size_t)c * N_ + n0 + s + t0);
      float* kd = &ks[c * TSP_ + t0];
      kd[0] = bf_lo(uk.x); kd[1] = bf_hi(uk.x); kd[2] = bf_lo(uk.y); kd[3] = bf_hi(uk.y);
      kd[4] = bf_lo(uk.z); kd[5] = bf_hi(uk.z); kd[6] = bf_lo(uk.w); kd[7] = bf_hi(uk.w);
    }
    __syncthreads();
#pragma unroll 8
    for (int t = 0; t < 128; ++t) {
      const float q0 = qs[i0 * TSP_ + t], q1 = qs[(i0 + 1) * TSP_ + t];
      const float k0 = ks[j0 * TSP_ + t], k1 = ks[(j0 + 1) * TSP_ + t];
      a00 += q0 * k0; a01 += q0 * k1; a10 += q1 * k0; a11 += q1 * k1;
    }
  }
  float* ap = attn_raw + ((size_t)(b * HEAD_ + h)) * 1024;
  atomicAdd(&ap[i0 * 32 + j0],           a00);
  atomicAdd(&ap[i0 * 32 + j0 + 1],       a01);
  atomicAdd(&ap[(i0 + 1) * 32 + j0],     a10);
  atomicAdd(&ap[(i0 + 1) * 32 + j0 + 1], a11);
}

// ---------------- K5: scale by inv norms, softmax over j (32) ---------------
__global__ __launch_bounds__(256) void k_softmax(
    const float* __restrict__ attn_raw, const float* __restrict__ inv,
    float* __restrict__ attn_out) {
  const int tid = threadIdx.x;
  const int R = blockIdx.x * 8 + (tid >> 5);   // 0..383 = (b*3+h)*32+i
  const int j = tid & 31;
  const int b = R / 96, rem = R % 96;
  const int h = rem / 32, i = rem % 32;
  const float invq = inv[b * 192 + h * 32 + i];
  const float invk = inv[b * 192 + 96 + h * 32 + j];
  float v = attn_raw[R * 32 + j] * invq * invk;   // TEMP = 1
  float m = v;
#pragma unroll
  for (int off = 16; off > 0; off >>= 1) m = fmaxf(m, __shfl_xor(m, off, 32));
  const float e = __expf(v - m);
  float s = e;
#pragma unroll
  for (int off = 16; off > 0; off >>= 1) s += __shfl_xor(s, off, 32);
  attn_out[R * 32 + j] = e / s;
}

// ---------------- K6: out_mid[b, h*32+i, n] = sum_j attn[i,j] * v[j,n] ------
__global__ __launch_bounds__(256) void k_attn_v(
    const unsigned short* __restrict__ dw, const float* __restrict__ attn,
    float* __restrict__ out_mid) {
  __shared__ float as_[1024];
  const int tid = threadIdx.x;
  const int h = blockIdx.y, b = blockIdx.z;
  const int n = blockIdx.x * 256 + tid;
  const float* ap = attn + ((size_t)(b * HEAD_ + h)) * 1024;
  for (int l = tid; l < 1024; l += 256) as_[l] = ap[l];
  __syncthreads();
  const unsigned short* vp = dw + ((size_t)(b * C3_ + 2 * C_ + h * HC_)) * N_ + n;
  float acc[32];
#pragma unroll
  for (int i = 0; i < 32; ++i) acc[i] = 0.f;
#pragma unroll
  for (int j = 0; j < 32; ++j) {
    const float vv = bf2f(vp[(size_t)j * N_]);
#pragma unroll
    for (int i = 0; i < 32; ++i) acc[i] += as_[i * 32 + j] * vv;
  }
  float* op = out_mid + ((size_t)(b * C_ + h * HC_)) * N_ + n;
#pragma unroll
  for (int i = 0; i < 32; ++i) op[(size_t)i * N_] = acc[i];
}

// ---------------- K7: out = proj_w @ out_mid + proj_b (96 -> 96, IN-PLACE) --
// NOTE: no __restrict__ — 'x' and 'out' alias (in-place on d_out). All 96
// channel values are loaded to registers before any store (program order).
__global__ __launch_bounds__(256) void k_pointwise96(
    const float* x, const float* __restrict__ w,
    const float* __restrict__ bias, float* out) {
  __shared__ float wsh[8 * 96];
  const int tid = threadIdx.x;
  const int b = blockIdx.y;
  const int n = blockIdx.x * 256 + tid;
  const float* xp = x + (size_t)b * C_ * N_ + n;
  float xr[96];
#pragma unroll
  for (int c = 0; c < 96; ++c) xr[c] = xp[(size_t)c * N_];
  for (int ob = 0; ob < 12; ++ob) {
    __syncthreads();
    for (int i = tid; i < 768; i += 256) wsh[i] = w[ob * 768 + i];
    __syncthreads();
    float acc[8];
#pragma unroll
    for (int o = 0; o < 8; ++o) acc[o] = bias[ob * 8 + o];
#pragma unroll
    for (int c = 0; c < 96; ++c) {
      const float xv = xr[c];
#pragma unroll
      for (int o = 0; o < 8; ++o) acc[o] += wsh[o * 96 + c] * xv;
    }
#pragma unroll
    for (int o = 0; o < 8; ++o)
      out[((size_t)b * C_ + ob * 8 + o) * N_ + n] = acc[o];
  }
}

extern "C" void kernel_launch(void* const* d_in, const int* in_sizes, int n_in,
                              void* d_out, int out_size, void* d_ws, size_t ws_size,
                              hipStream_t stream) {
  const float* x      = (const float*)d_in[0];
  const float* qkv_w  = (const float*)d_in[1];
  const float* qkv_b  = (const float*)d_in[2];
  const float* dw_w   = (const float*)d_in[3];
  const float* dw_b   = (const float*)d_in[4];
  const float* proj_w = (const float*)d_in[5];
  const float* proj_b = (const float*)d_in[6];

  float* out      = (float*)d_out;                       // [4,96,256,256]
  float* attn_out = out + (size_t)B_ * C_ * N_;          // [4,3,32,32]

  // Workspace (151 MB + 52 KB):
  //   A:    B*288*N bf16 (ushort) = 150994944 B  — qkv, then dwconv IN-PLACE
  //   inv:  768 fp32
  //   araw: 12288 fp32
  unsigned short* A = (unsigned short*)d_ws;
  float* inv  = (float*)(A + (size_t)B_ * C3_ * N_);
  float* araw = inv + 768;

  k_pointwise288<<<dim3(N_ / 256, B_), 256, 0, stream>>>(x, qkv_w, qkv_b, A);
  k_dw_inplace<<<B_ * C3_, 256, 0, stream>>>(A, dw_w, dw_b);
  k_l2_inv<<<768, 256, 0, stream>>>(A, inv);
  k_zero<<<48, 256, 0, stream>>>(araw, HEAD_ * B_ * 1024);
  k_attn_partial<<<dim3(16, HEAD_, B_), 256, 0, stream>>>(A, araw);
  k_softmax<<<48, 256, 0, stream>>>(araw, inv, attn_out);
  k_attn_v<<<dim3(N_ / 256, HEAD_, B_), 256, 0, stream>>>(A, attn_out, out);
  k_pointwise96<<<dim3(N_ / 256, B_), 256, 0, stream>>>(out, proj_w, proj_b, out);
}

// Round 3
// 563.025 us; speedup vs baseline: 1.5487x; 1.5487x over previous
//
#include <hip/hip_runtime.h>
#include <hip/hip_bf16.h>

// Problem dims (StandardAttention): x[4,96,256,256], heads=3
#define B_  4
#define C_  96
#define H_  256
#define W_  256
#define N_  (H_*W_)      // 65536
#define C3_ 288
#define HEAD_ 3
#define HC_ 32
#define EPS_ 1e-12f

typedef __attribute__((ext_vector_type(8))) short short8;
typedef __attribute__((ext_vector_type(4))) float f32x4;

// ---- bf16 helpers (raw ushort storage) -------------------------------------
__device__ __forceinline__ unsigned short f2bf(float f) {
  unsigned u = __float_as_uint(f);
  u += 0x7fffu + ((u >> 16) & 1u);      // round-to-nearest-even
  return (unsigned short)(u >> 16);
}
__device__ __forceinline__ float bf2f(unsigned short h) {
  return __uint_as_float((unsigned)h << 16);
}
__device__ __forceinline__ float bf_lo(unsigned u) { return __uint_as_float(u << 16); }
__device__ __forceinline__ float bf_hi(unsigned u) { return __uint_as_float(u & 0xffff0000u); }
__device__ __forceinline__ unsigned pack_bf(float a, float b) {
  return (unsigned)f2bf(a) | ((unsigned)f2bf(b) << 16);
}

// ---------------- K0: fp32 -> bf16 cast (for weights) -----------------------
__global__ __launch_bounds__(256) void k_cast(
    const float* __restrict__ s, unsigned short* __restrict__ d, int n) {
  const int i = blockIdx.x * 256 + threadIdx.x;
  if (i < n) d[i] = f2bf(s[i]);
}

// ---------------- K1: qkv = qkv_w @ x + qkv_b  via MFMA ---------------------
// Block: 256 thr = 4 waves; waves = 2 pixel-groups x 2 M-halves (9 M-tiles).
// Grid-stride over 32-pixel tiles so the 55KB W stage is amortized.
__global__ __launch_bounds__(256) void k1_mfma(
    const float* __restrict__ x, const unsigned short* __restrict__ wbf,
    const float* __restrict__ bias, unsigned short* __restrict__ out) {
  __shared__ unsigned short Wl[C3_ * C_];     // 55296 B, [ch][k]
  __shared__ unsigned short Xt[32][C_];       // 6144 B,  [pix][k]
  __shared__ float Bl[C3_];
  const int tid = threadIdx.x;
  const int b = blockIdx.y;
  for (int i = tid; i < C3_ * C_; i += 256) Wl[i] = wbf[i];
  for (int i = tid; i < C3_; i += 256) Bl[i] = bias[i];
  const int lane = tid & 63;
  const int wv = tid >> 6;             // 0..3
  const int n0 = (wv & 1) * 16;        // pixel subgroup base
  const int mbase = (wv >> 1) * 144;   // 9 M-tiles of 16 channels
  const int l15 = lane & 15, quad = lane >> 4;
  for (int ti = blockIdx.x; ti < N_ / 32; ti += gridDim.x) {
    const int gp0 = ti * 32;
    __syncthreads();
    const float* xb = x + ((size_t)b * C_) * N_ + gp0;
#pragma unroll
    for (int l = 0; l < 12; ++l) {
      const int idx = tid + l * 256;
      const int c = idx >> 5, p = idx & 31;
      Xt[p][c] = f2bf(xb[(size_t)c * N_ + p]);
    }
    __syncthreads();
    f32x4 acc[9];
#pragma unroll
    for (int m = 0; m < 9; ++m) acc[m] = (f32x4){0.f, 0.f, 0.f, 0.f};
#pragma unroll
    for (int kc = 0; kc < 3; ++kc) {
      const short8 bfr = *reinterpret_cast<const short8*>(&Xt[n0 + l15][kc * 32 + quad * 8]);
#pragma unroll
      for (int m = 0; m < 9; ++m) {
        const short8 afr = *reinterpret_cast<const short8*>(
            &Wl[(mbase + m * 16 + l15) * C_ + kc * 32 + quad * 8]);
        acc[m] = __builtin_amdgcn_mfma_f32_16x16x32_bf16(afr, bfr, acc[m], 0, 0, 0);
      }
    }
    unsigned short* ob = out + (size_t)b * C3_ * N_ + gp0 + n0 + l15;
#pragma unroll
    for (int m = 0; m < 9; ++m) {
      const int chb = mbase + m * 16 + quad * 4;
#pragma unroll
      for (int r = 0; r < 4; ++r)
        ob[(size_t)(chb + r) * N_] = f2bf(acc[m][r] + Bl[chb + r]);
    }
  }
}

// ---------------- K2: 3x3 depthwise conv, pad=1, IN-PLACE on bf16 plane -----
__global__ __launch_bounds__(256) void k_dw_inplace(
    unsigned short* a, const float* __restrict__ w9,
    const float* __restrict__ bias) {
  const int bc = blockIdx.x;            // 0..1151
  const int ch = bc % C3_;
  unsigned short* p = a + (size_t)bc * N_;
  const int tid = threadIdx.x;
  const int tr = tid >> 5;              // 0..7
  const int tc = tid & 31;
  const int x0 = tc * 8;
  __shared__ float ring[11][W_];        // slots 0..9: rows (mod 10); slot 10: zeros
  float wv[9];
#pragma unroll
  for (int i = 0; i < 9; ++i) wv[i] = w9[ch * 9 + i];
  const float bv = bias[ch];
  ring[10][tid] = 0.f;
  {
    const uint4 u = *reinterpret_cast<const uint4*>(p + (size_t)tr * W_ + x0);
    float* d = &ring[tr][x0];
    d[0] = bf_lo(u.x); d[1] = bf_hi(u.x); d[2] = bf_lo(u.y); d[3] = bf_hi(u.y);
    d[4] = bf_lo(u.z); d[5] = bf_hi(u.z); d[6] = bf_lo(u.w); d[7] = bf_hi(u.w);
    if (tr == 0) {
      const uint4 v = *reinterpret_cast<const uint4*>(p + (size_t)8 * W_ + x0);
      float* e = &ring[8][x0];
      e[0] = bf_lo(v.x); e[1] = bf_hi(v.x); e[2] = bf_lo(v.y); e[3] = bf_hi(v.y);
      e[4] = bf_lo(v.z); e[5] = bf_hi(v.z); e[6] = bf_lo(v.w); e[7] = bf_hi(v.w);
    }
  }
  __syncthreads();
  for (int y = 0; y < 256; y += 8) {
    const int r = y + tr;
    const float* tp = (r - 1 >= 0) ? ring[(r - 1) % 10] : ring[10];
    const float* mp = ring[r % 10];
    const float* bp = (r + 1 < 256) ? ring[(r + 1) % 10] : ring[10];
    float vt[10], vm[10], vb[10];
#pragma unroll
    for (int j = 0; j < 10; ++j) {
      const int xx = x0 - 1 + j;
      const bool in = (unsigned)xx < 256u;
      vt[j] = in ? tp[xx] : 0.f;
      vm[j] = in ? mp[xx] : 0.f;
      vb[j] = in ? bp[xx] : 0.f;
    }
    float o[8];
#pragma unroll
    for (int j = 0; j < 8; ++j)
      o[j] = bv + wv[0] * vt[j] + wv[1] * vt[j + 1] + wv[2] * vt[j + 2]
                + wv[3] * vm[j] + wv[4] * vm[j + 1] + wv[5] * vm[j + 2]
                + wv[6] * vb[j] + wv[7] * vb[j + 1] + wv[8] * vb[j + 2];
    __syncthreads();
    uint4 st;
    st.x = pack_bf(o[0], o[1]); st.y = pack_bf(o[2], o[3]);
    st.z = pack_bf(o[4], o[5]); st.w = pack_bf(o[6], o[7]);
    *reinterpret_cast<uint4*>(p + (size_t)r * W_ + x0) = st;
    const int nr = y + 9 + tr;
    if (nr < 256) {
      const uint4 u = *reinterpret_cast<const uint4*>(p + (size_t)nr * W_ + x0);
      float* d = &ring[nr % 10][x0];
      d[0] = bf_lo(u.x); d[1] = bf_hi(u.x); d[2] = bf_lo(u.y); d[3] = bf_hi(u.y);
      d[4] = bf_lo(u.z); d[5] = bf_hi(u.z); d[6] = bf_lo(u.w); d[7] = bf_hi(u.w);
    }
    __syncthreads();
  }
}

// ---------------- K3: inverse L2 norms for q,k rows (768 rows of 65536) -----
__global__ __launch_bounds__(256) void k_l2_inv(
    const unsigned short* __restrict__ dw, float* __restrict__ inv) {
  const int r = blockIdx.x;
  const int b = r / 192, c = r % 192;
  const uint4* pv = reinterpret_cast<const uint4*>(dw + ((size_t)(b * C3_ + c)) * N_);
  float s = 0.f;
  for (int i = threadIdx.x; i < N_ / 8; i += 256) {
    const uint4 u = pv[i];
    float v0 = bf_lo(u.x), v1 = bf_hi(u.x), v2 = bf_lo(u.y), v3 = bf_hi(u.y);
    float v4 = bf_lo(u.z), v5 = bf_hi(u.z), v6 = bf_lo(u.w), v7 = bf_hi(u.w);
    s += v0 * v0 + v1 * v1 + v2 * v2 + v3 * v3 + v4 * v4 + v5 * v5 + v6 * v6 + v7 * v7;
  }
#pragma unroll
  for (int off = 32; off > 0; off >>= 1) s += __shfl_down(s, off, 64);
  __shared__ float red[4];
  if ((threadIdx.x & 63) == 0) red[threadIdx.x >> 6] = s;
  __syncthreads();
  if (threadIdx.x == 0) {
    float t = red[0] + red[1] + red[2] + red[3];
    inv[r] = 1.0f / fmaxf(sqrtf(t), EPS_);
  }
}

__global__ __launch_bounds__(256) void k_zero(float* __restrict__ p, int n) {
  const int i = blockIdx.x * 256 + threadIdx.x;
  if (i < n) p[i] = 0.f;
}

// ---------------- K4: attn_raw[b,h,i,j] += sum_n q[i,n]*k[j,n]  (split-K) ---
#define TSP_ 129
__global__ __launch_bounds__(256) void k_attn_partial(
    const unsigned short* __restrict__ dw, float* __restrict__ attn_raw) {
  __shared__ float qs[32 * TSP_];
  __shared__ float ks[32 * TSP_];
  const int tid = threadIdx.x;
  const int h = blockIdx.y, b = blockIdx.z;
  const unsigned short* qp = dw + ((size_t)(b * C3_ + h * HC_)) * N_;
  const unsigned short* kp = dw + ((size_t)(b * C3_ + C_ + h * HC_)) * N_;
  const int n0 = blockIdx.x * 4096;
  const int i0 = (tid >> 4) << 1, j0 = (tid & 15) << 1;
  float a00 = 0.f, a01 = 0.f, a10 = 0.f, a11 = 0.f;
  for (int s = 0; s < 4096; s += 128) {
    __syncthreads();
#pragma unroll
    for (int l = 0; l < 2; ++l) {
      const int idx = tid + l * 256;
      const int c = idx >> 4;
      const int t0 = (idx & 15) * 8;
      const uint4 uq = *reinterpret_cast<const uint4*>(qp + (size_t)c * N_ + n0 + s + t0);
      float* qd = &qs[c * TSP_ + t0];
      qd[0] = bf_lo(uq.x); qd[1] = bf_hi(uq.x); qd[2] = bf_lo(uq.y); qd[3] = bf_hi(uq.y);
      qd[4] = bf_lo(uq.z); qd[5] = bf_hi(uq.z); qd[6] = bf_lo(uq.w); qd[7] = bf_hi(uq.w);
      const uint4 uk = *reinterpret_cast<const uint4*>(kp + (size_t)c * N_ + n0 + s + t0);
      float* kd = &ks[c * TSP_ + t0];
      kd[0] = bf_lo(uk.x); kd[1] = bf_hi(uk.x); kd[2] = bf_lo(uk.y); kd[3] = bf_hi(uk.y);
      kd[4] = bf_lo(uk.z); kd[5] = bf_hi(uk.z); kd[6] = bf_lo(uk.w); kd[7] = bf_hi(uk.w);
    }
    __syncthreads();
#pragma unroll 8
    for (int t = 0; t < 128; ++t) {
      const float q0 = qs[i0 * TSP_ + t], q1 = qs[(i0 + 1) * TSP_ + t];
      const float k0 = ks[j0 * TSP_ + t], k1 = ks[(j0 + 1) * TSP_ + t];
      a00 += q0 * k0; a01 += q0 * k1; a10 += q1 * k0; a11 += q1 * k1;
    }
  }
  float* ap = attn_raw + ((size_t)(b * HEAD_ + h)) * 1024;
  atomicAdd(&ap[i0 * 32 + j0],           a00);
  atomicAdd(&ap[i0 * 32 + j0 + 1],       a01);
  atomicAdd(&ap[(i0 + 1) * 32 + j0],     a10);
  atomicAdd(&ap[(i0 + 1) * 32 + j0 + 1], a11);
}

// ---------------- K5: scale by inv norms, softmax over j (32) ---------------
__global__ __launch_bounds__(256) void k_softmax(
    const float* __restrict__ attn_raw, const float* __restrict__ inv,
    float* __restrict__ attn_out) {
  const int tid = threadIdx.x;
  const int R = blockIdx.x * 8 + (tid >> 5);
  const int j = tid & 31;
  const int b = R / 96, rem = R % 96;
  const int h = rem / 32, i = rem % 32;
  const float invq = inv[b * 192 + h * 32 + i];
  const float invk = inv[b * 192 + 96 + h * 32 + j];
  float v = attn_raw[R * 32 + j] * invq * invk;
  float m = v;
#pragma unroll
  for (int off = 16; off > 0; off >>= 1) m = fmaxf(m, __shfl_xor(m, off, 32));
  const float e = __expf(v - m);
  float s = e;
#pragma unroll
  for (int off = 16; off > 0; off >>= 1) s += __shfl_xor(s, off, 32);
  attn_out[R * 32 + j] = e / s;
}

// ---------------- K6: out_mid (bf16, into A's q-region) ---------------------
__global__ __launch_bounds__(256) void k_attn_v(
    const unsigned short* __restrict__ dwv, const float* __restrict__ attn,
    unsigned short* __restrict__ out_mid /* == A q-region, disjoint from v */) {
  __shared__ float as_[1024];
  const int tid = threadIdx.x;
  const int h = blockIdx.y, b = blockIdx.z;
  const int n = blockIdx.x * 256 + tid;
  const float* ap = attn + ((size_t)(b * HEAD_ + h)) * 1024;
  for (int l = tid; l < 1024; l += 256) as_[l] = ap[l];
  __syncthreads();
  const unsigned short* vp = dwv + ((size_t)(b * C3_ + 2 * C_ + h * HC_)) * N_ + n;
  float acc[32];
#pragma unroll
  for (int i = 0; i < 32; ++i) acc[i] = 0.f;
#pragma unroll
  for (int j = 0; j < 32; ++j) {
    const float vv = bf2f(vp[(size_t)j * N_]);
#pragma unroll
    for (int i = 0; i < 32; ++i) acc[i] += as_[i * 32 + j] * vv;
  }
  unsigned short* op = out_mid + ((size_t)(b * C3_) + h * HC_) * N_ + n;
#pragma unroll
  for (int i = 0; i < 32; ++i) op[(size_t)i * N_] = f2bf(acc[i]);
}

// ---------------- K7: out = proj_w @ out_mid + proj_b via MFMA --------------
__global__ __launch_bounds__(256) void k7_mfma(
    const unsigned short* __restrict__ mid /* A base */,
    const unsigned short* __restrict__ wbf,
    const float* __restrict__ bias, float* __restrict__ out) {
  __shared__ unsigned short Wl[C_ * C_];      // 18432 B
  __shared__ unsigned short Xt[64][C_];       // 12288 B
  __shared__ float Bl[C_];
  const int tid = threadIdx.x;
  const int b = blockIdx.y;
  for (int i = tid; i < C_ * C_; i += 256) Wl[i] = wbf[i];
  if (tid < C_) Bl[tid] = bias[tid];
  const int lane = tid & 63;
  const int wv = tid >> 6;
  const int n0 = wv * 16;
  const int l15 = lane & 15, quad = lane >> 4;
  for (int ti = blockIdx.x; ti < N_ / 64; ti += gridDim.x) {
    const int gp0 = ti * 64;
    __syncthreads();
    const unsigned short* xb = mid + (size_t)b * C3_ * N_ + gp0;
#pragma unroll
    for (int l = 0; l < 24; ++l) {
      const int idx = tid + l * 256;
      const int c = idx >> 6, p = idx & 63;
      Xt[p][c] = xb[(size_t)c * N_ + p];
    }
    __syncthreads();
    f32x4 acc[6];
#pragma unroll
    for (int m = 0; m < 6; ++m) acc[m] = (f32x4){0.f, 0.f, 0.f, 0.f};
#pragma unroll
    for (int kc = 0; kc < 3; ++kc) {
      const short8 bfr = *reinterpret_cast<const short8*>(&Xt[n0 + l15][kc * 32 + quad * 8]);
#pragma unroll
      for (int m = 0; m < 6; ++m) {
        const short8 afr = *reinterpret_cast<const short8*>(
            &Wl[(m * 16 + l15) * C_ + kc * 32 + quad * 8]);
        acc[m] = __builtin_amdgcn_mfma_f32_16x16x32_bf16(afr, bfr, acc[m], 0, 0, 0);
      }
    }
    float* ob = out + (size_t)b * C_ * N_ + gp0 + n0 + l15;
#pragma unroll
    for (int m = 0; m < 6; ++m) {
      const int chb = m * 16 + quad * 4;
#pragma unroll
      for (int r = 0; r < 4; ++r)
        ob[(size_t)(chb + r) * N_] = acc[m][r] + Bl[chb + r];
    }
  }
}

extern "C" void kernel_launch(void* const* d_in, const int* in_sizes, int n_in,
                              void* d_out, int out_size, void* d_ws, size_t ws_size,
                              hipStream_t stream) {
  const float* x      = (const float*)d_in[0];
  const float* qkv_w  = (const float*)d_in[1];
  const float* qkv_b  = (const float*)d_in[2];
  const float* dw_w   = (const float*)d_in[3];
  const float* dw_b   = (const float*)d_in[4];
  const float* proj_w = (const float*)d_in[5];
  const float* proj_b = (const float*)d_in[6];

  float* out      = (float*)d_out;                       // [4,96,256,256]
  float* attn_out = out + (size_t)B_ * C_ * N_;          // [4,3,32,32]

  // Workspace (~151 MB):
  //   A:     B*288*N bf16 — qkv, dwconv IN-PLACE, then out_mid into q-region
  //   inv:   768 fp32 | araw: 12288 fp32 | wq_bf: 27648 bf16 | wp_bf: 9216 bf16
  unsigned short* A = (unsigned short*)d_ws;
  float* inv   = (float*)(A + (size_t)B_ * C3_ * N_);
  float* araw  = inv + 768;
  unsigned short* wq_bf = (unsigned short*)(araw + 12288);
  unsigned short* wp_bf = wq_bf + C3_ * C_;

  k_cast<<<108, 256, 0, stream>>>(qkv_w, wq_bf, C3_ * C_);
  k_cast<<<36, 256, 0, stream>>>(proj_w, wp_bf, C_ * C_);
  k1_mfma<<<dim3(512, B_), 256, 0, stream>>>(x, wq_bf, qkv_b, A);
  k_dw_inplace<<<B_ * C3_, 256, 0, stream>>>(A, dw_w, dw_b);
  k_l2_inv<<<768, 256, 0, stream>>>(A, inv);
  k_zero<<<48, 256, 0, stream>>>(araw, HEAD_ * B_ * 1024);
  k_attn_partial<<<dim3(16, HEAD_, B_), 256, 0, stream>>>(A, araw);
  k_softmax<<<48, 256, 0, stream>>>(araw, inv, attn_out);
  k_attn_v<<<dim3(N_ / 256, HEAD_, B_), 256, 0, stream>>>(A, attn_out, A);
  k7_mfma<<<dim3(256, B_), 256, 0, stream>>>(A, wp_bf, proj_b, out);
}

// Round 4
// 474.221 us; speedup vs baseline: 1.8388x; 1.1873x over previous
//
#include <hip/hip_runtime.h>
#include <hip/hip_bf16.h>

// Problem dims (StandardAttention): x[4,96,256,256], heads=3
#define B_  4
#define C_  96
#define H_  256
#define W_  256
#define N_  (H_*W_)      // 65536
#define C3_ 288
#define HEAD_ 3
#define HC_ 32
#define EPS_ 1e-12f
#define XP_ 104          // padded LDS row stride (ushorts): word-stride 52 -> conflict-free b128

typedef __attribute__((ext_vector_type(8))) short short8;
typedef __attribute__((ext_vector_type(4))) float f32x4;

// ---- bf16 helpers (raw ushort storage) -------------------------------------
__device__ __forceinline__ unsigned short f2bf(float f) {
  unsigned u = __float_as_uint(f);
  u += 0x7fffu + ((u >> 16) & 1u);      // round-to-nearest-even
  return (unsigned short)(u >> 16);
}
__device__ __forceinline__ float bf2f(unsigned short h) {
  return __uint_as_float((unsigned)h << 16);
}
__device__ __forceinline__ float bf_lo(unsigned u) { return __uint_as_float(u << 16); }
__device__ __forceinline__ float bf_hi(unsigned u) { return __uint_as_float(u & 0xffff0000u); }
__device__ __forceinline__ unsigned pack_bf(float a, float b) {
  return (unsigned)f2bf(a) | ((unsigned)f2bf(b) << 16);
}

// ---------------- K0: fp32 -> bf16 cast (for weights) -----------------------
__global__ __launch_bounds__(256) void k_cast(
    const float* __restrict__ s, unsigned short* __restrict__ d, int n) {
  const int i = blockIdx.x * 256 + threadIdx.x;
  if (i < n) d[i] = f2bf(s[i]);
}

// ---------------- K1: qkv = qkv_w @ x + qkv_b  via MFMA ---------------------
__global__ __launch_bounds__(256) void k1_mfma(
    const float* __restrict__ x, const unsigned short* __restrict__ wbf,
    const float* __restrict__ bias, unsigned short* __restrict__ out) {
  __shared__ unsigned short Wl[C3_ * XP_];    // 59904 B, [ch][k] stride 104
  __shared__ unsigned short Xt[32 * XP_];     // 6656 B,  [pix][k] stride 104
  __shared__ float Bl[C3_];
  const int tid = threadIdx.x;
  const int b = blockIdx.y;
  for (int i = tid; i < C3_ * C_; i += 256) {
    const int c = i / 96, k = i % 96;
    Wl[c * XP_ + k] = wbf[i];
  }
  for (int i = tid; i < C3_; i += 256) Bl[i] = bias[i];
  const int lane = tid & 63;
  const int wv = tid >> 6;             // 0..3
  const int n0 = (wv & 1) * 16;        // pixel subgroup base
  const int mbase = (wv >> 1) * 144;   // 9 M-tiles of 16 channels
  const int l15 = lane & 15, quad = lane >> 4;
  for (int ti = blockIdx.x; ti < N_ / 32; ti += gridDim.x) {
    const int gp0 = ti * 32;
    __syncthreads();
    const float* xb = x + ((size_t)b * C_) * N_ + gp0;
#pragma unroll
    for (int l = 0; l < 12; ++l) {
      const int idx = tid + l * 256;
      const int c = idx >> 5, p = idx & 31;
      Xt[p * XP_ + c] = f2bf(xb[(size_t)c * N_ + p]);
    }
    __syncthreads();
    f32x4 acc[9];
#pragma unroll
    for (int m = 0; m < 9; ++m) acc[m] = (f32x4){0.f, 0.f, 0.f, 0.f};
#pragma unroll
    for (int kc = 0; kc < 3; ++kc) {
      const short8 bfr = *reinterpret_cast<const short8*>(&Xt[(n0 + l15) * XP_ + kc * 32 + quad * 8]);
#pragma unroll
      for (int m = 0; m < 9; ++m) {
        const short8 afr = *reinterpret_cast<const short8*>(
            &Wl[(mbase + m * 16 + l15) * XP_ + kc * 32 + quad * 8]);
        acc[m] = __builtin_amdgcn_mfma_f32_16x16x32_bf16(afr, bfr, acc[m], 0, 0, 0);
      }
    }
    unsigned short* ob = out + (size_t)b * C3_ * N_ + gp0 + n0 + l15;
#pragma unroll
    for (int m = 0; m < 9; ++m) {
      const int chb = mbase + m * 16 + quad * 4;
#pragma unroll
      for (int r = 0; r < 4; ++r)
        ob[(size_t)(chb + r) * N_] = f2bf(acc[m][r] + Bl[chb + r]);
    }
  }
}

// ---------------- K2: 3x3 depthwise conv IN-PLACE, register-rolling ---------
// One block per (b,ch) plane; thread (tr,tc) owns cols [tc*8, tc*8+8) and
// rows [tr*32, tr*32+32). No LDS: 3-row x 10-col register window, halo via
// global loads. Boundary rows preloaded before the single barrier so the
// in-place update is race-free (intra-segment reads lead writes by 2 rows,
// lanes of one segment are in one wave = lockstep). Fuses sumsq -> inv.
__global__ __launch_bounds__(256) void k_dw_reg(
    unsigned short* a, const float* __restrict__ w9,
    const float* __restrict__ bias, float* __restrict__ inv) {
  const int bc = blockIdx.x;            // 0..1151
  const int ch = bc % C3_;
  unsigned short* p = a + (size_t)bc * N_;
  const int tid = threadIdx.x;
  const int tr = tid >> 5;              // 0..7 row segment
  const int tc = tid & 31;
  const int x0 = tc * 8;
  const int y0 = tr * 32;
  float wv[9];
#pragma unroll
  for (int i = 0; i < 9; ++i) wv[i] = w9[ch * 9 + i];
  const float bv = bias[ch];

  auto load_row = [&](int y, float* d) {
    if ((unsigned)y >= 256u) {
#pragma unroll
      for (int j = 0; j < 10; ++j) d[j] = 0.f;
      return;
    }
    const unsigned short* rp = p + (size_t)y * W_;
    const uint4 u = *reinterpret_cast<const uint4*>(rp + x0);
    d[1] = bf_lo(u.x); d[2] = bf_hi(u.x); d[3] = bf_lo(u.y); d[4] = bf_hi(u.y);
    d[5] = bf_lo(u.z); d[6] = bf_hi(u.z); d[7] = bf_lo(u.w); d[8] = bf_hi(u.w);
    d[0] = (tc > 0) ? bf2f(rp[x0 - 1]) : 0.f;
    d[9] = (tc < 31) ? bf2f(rp[x0 + 8]) : 0.f;
  };

  float rm[10], rc[10], rn[10], rb[10];
  load_row(y0 - 1, rm);
  load_row(y0, rc);
  load_row(y0 + 1, rn);
  load_row(y0 + 32, rb);     // bottom boundary: original data, pre-barrier
  __syncthreads();           // all preloads done before any write

  float ss = 0.f;
  for (int y = y0; y < y0 + 32; ++y) {
    float o[8];
#pragma unroll
    for (int j = 0; j < 8; ++j) {
      o[j] = bv + wv[0] * rm[j] + wv[1] * rm[j + 1] + wv[2] * rm[j + 2]
                + wv[3] * rc[j] + wv[4] * rc[j + 1] + wv[5] * rc[j + 2]
                + wv[6] * rn[j] + wv[7] * rn[j + 1] + wv[8] * rn[j + 2];
      ss += o[j] * o[j];
    }
    uint4 st;
    st.x = pack_bf(o[0], o[1]); st.y = pack_bf(o[2], o[3]);
    st.z = pack_bf(o[4], o[5]); st.w = pack_bf(o[6], o[7]);
    *reinterpret_cast<uint4*>(p + (size_t)y * W_ + x0) = st;
#pragma unroll
    for (int j = 0; j < 10; ++j) { rm[j] = rc[j]; rc[j] = rn[j]; }
    const int ny = y + 2;
    if (ny <= y0 + 31) {
      load_row(ny, rn);                      // own segment: still original
    } else if (ny == y0 + 32) {
#pragma unroll
      for (int j = 0; j < 10; ++j) rn[j] = rb[j];
    }
  }
  // block reduction of sum of squares -> inv (q,k channels only)
#pragma unroll
  for (int off = 32; off > 0; off >>= 1) ss += __shfl_down(ss, off, 64);
  __shared__ float red[4];
  if ((tid & 63) == 0) red[tid >> 6] = ss;
  __syncthreads();
  if (tid == 0 && ch < 192) {
    const float t = red[0] + red[1] + red[2] + red[3];
    const int b = bc / C3_;
    inv[b * 192 + ch] = 1.0f / fmaxf(sqrtf(t), EPS_);
  }
}

__global__ __launch_bounds__(256) void k_zero(float* __restrict__ p, int n) {
  const int i = blockIdx.x * 256 + threadIdx.x;
  if (i < n) p[i] = 0.f;
}

// ---------------- K4: attn_raw[b,h,i,j] += sum_n q[i,n]*k[j,n]  (split-K) ---
#define TSP_ 129
__global__ __launch_bounds__(256) void k_attn_partial(
    const unsigned short* __restrict__ dw, float* __restrict__ attn_raw) {
  __shared__ float qs[32 * TSP_];
  __shared__ float ks[32 * TSP_];
  const int tid = threadIdx.x;
  const int h = blockIdx.y, b = blockIdx.z;
  const unsigned short* qp = dw + ((size_t)(b * C3_ + h * HC_)) * N_;
  const unsigned short* kp = dw + ((size_t)(b * C3_ + C_ + h * HC_)) * N_;
  const int n0 = blockIdx.x * 4096;
  const int i0 = (tid >> 4) << 1, j0 = (tid & 15) << 1;
  float a00 = 0.f, a01 = 0.f, a10 = 0.f, a11 = 0.f;
  for (int s = 0; s < 4096; s += 128) {
    __syncthreads();
#pragma unroll
    for (int l = 0; l < 2; ++l) {
      const int idx = tid + l * 256;
      const int c = idx >> 4;
      const int t0 = (idx & 15) * 8;
      const uint4 uq = *reinterpret_cast<const uint4*>(qp + (size_t)c * N_ + n0 + s + t0);
      float* qd = &qs[c * TSP_ + t0];
      qd[0] = bf_lo(uq.x); qd[1] = bf_hi(uq.x); qd[2] = bf_lo(uq.y); qd[3] = bf_hi(uq.y);
      qd[4] = bf_lo(uq.z); qd[5] = bf_hi(uq.z); qd[6] = bf_lo(uq.w); qd[7] = bf_hi(uq.w);
      const uint4 uk = *reinterpret_cast<const uint4*>(kp + (size_t)c * N_ + n0 + s + t0);
      float* kd = &ks[c * TSP_ + t0];
      kd[0] = bf_lo(uk.x); kd[1] = bf_hi(uk.x); kd[2] = bf_lo(uk.y); kd[3] = bf_hi(uk.y);
      kd[4] = bf_lo(uk.z); kd[5] = bf_hi(uk.z); kd[6] = bf_lo(uk.w); kd[7] = bf_hi(uk.w);
    }
    __syncthreads();
#pragma unroll 8
    for (int t = 0; t < 128; ++t) {
      const float q0 = qs[i0 * TSP_ + t], q1 = qs[(i0 + 1) * TSP_ + t];
      const float k0 = ks[j0 * TSP_ + t], k1 = ks[(j0 + 1) * TSP_ + t];
      a00 += q0 * k0; a01 += q0 * k1; a10 += q1 * k0; a11 += q1 * k1;
    }
  }
  float* ap = attn_raw + ((size_t)(b * HEAD_ + h)) * 1024;
  atomicAdd(&ap[i0 * 32 + j0],           a00);
  atomicAdd(&ap[i0 * 32 + j0 + 1],       a01);
  atomicAdd(&ap[(i0 + 1) * 32 + j0],     a10);
  atomicAdd(&ap[(i0 + 1) * 32 + j0 + 1], a11);
}

// ---------------- K5: scale by inv norms, softmax over j (32) ---------------
__global__ __launch_bounds__(256) void k_softmax(
    const float* __restrict__ attn_raw, const float* __restrict__ inv,
    float* __restrict__ attn_out) {
  const int tid = threadIdx.x;
  const int R = blockIdx.x * 8 + (tid >> 5);
  const int j = tid & 31;
  const int b = R / 96, rem = R % 96;
  const int h = rem / 32, i = rem % 32;
  const float invq = inv[b * 192 + h * 32 + i];
  const float invk = inv[b * 192 + 96 + h * 32 + j];
  float v = attn_raw[R * 32 + j] * invq * invk;
  float m = v;
#pragma unroll
  for (int off = 16; off > 0; off >>= 1) m = fmaxf(m, __shfl_xor(m, off, 32));
  const float e = __expf(v - m);
  float s = e;
#pragma unroll
  for (int off = 16; off > 0; off >>= 1) s += __shfl_xor(s, off, 32);
  attn_out[R * 32 + j] = e / s;
}

// ---------------- K6: out_mid (bf16, into A's q-region) ---------------------
__global__ __launch_bounds__(256) void k_attn_v(
    const unsigned short* __restrict__ dwv, const float* __restrict__ attn,
    unsigned short* __restrict__ out_mid) {
  __shared__ float as_[1024];
  const int tid = threadIdx.x;
  const int h = blockIdx.y, b = blockIdx.z;
  const int n = blockIdx.x * 256 + tid;
  const float* ap = attn + ((size_t)(b * HEAD_ + h)) * 1024;
  for (int l = tid; l < 1024; l += 256) as_[l] = ap[l];
  __syncthreads();
  const unsigned short* vp = dwv + ((size_t)(b * C3_ + 2 * C_ + h * HC_)) * N_ + n;
  float acc[32];
#pragma unroll
  for (int i = 0; i < 32; ++i) acc[i] = 0.f;
#pragma unroll
  for (int j = 0; j < 32; ++j) {
    const float vv = bf2f(vp[(size_t)j * N_]);
#pragma unroll
    for (int i = 0; i < 32; ++i) acc[i] += as_[i * 32 + j] * vv;
  }
  unsigned short* op = out_mid + ((size_t)(b * C3_) + h * HC_) * N_ + n;
#pragma unroll
  for (int i = 0; i < 32; ++i) op[(size_t)i * N_] = f2bf(acc[i]);
}

// ---------------- K7: out = proj_w @ out_mid + proj_b via MFMA --------------
__global__ __launch_bounds__(256) void k7_mfma(
    const unsigned short* __restrict__ mid,
    const unsigned short* __restrict__ wbf,
    const float* __restrict__ bias, float* __restrict__ out) {
  __shared__ unsigned short Wl[C_ * XP_];     // 19968 B
  __shared__ unsigned short Xt[64 * XP_];     // 13312 B
  __shared__ float Bl[C_];
  const int tid = threadIdx.x;
  const int b = blockIdx.y;
  for (int i = tid; i < C_ * C_; i += 256) {
    const int c = i / 96, k = i % 96;
    Wl[c * XP_ + k] = wbf[i];
  }
  if (tid < C_) Bl[tid] = bias[tid];
  const int lane = tid & 63;
  const int wv = tid >> 6;
  const int n0 = wv * 16;
  const int l15 = lane & 15, quad = lane >> 4;
  for (int ti = blockIdx.x; ti < N_ / 64; ti += gridDim.x) {
    const int gp0 = ti * 64;
    __syncthreads();
    const unsigned short* xb = mid + (size_t)b * C3_ * N_ + gp0;
#pragma unroll
    for (int l = 0; l < 24; ++l) {
      const int idx = tid + l * 256;
      const int c = idx >> 6, p = idx & 63;
      Xt[p * XP_ + c] = xb[(size_t)c * N_ + p];
    }
    __syncthreads();
    f32x4 acc[6];
#pragma unroll
    for (int m = 0; m < 6; ++m) acc[m] = (f32x4){0.f, 0.f, 0.f, 0.f};
#pragma unroll
    for (int kc = 0; kc < 3; ++kc) {
      const short8 bfr = *reinterpret_cast<const short8*>(&Xt[(n0 + l15) * XP_ + kc * 32 + quad * 8]);
#pragma unroll
      for (int m = 0; m < 6; ++m) {
        const short8 afr = *reinterpret_cast<const short8*>(
            &Wl[(m * 16 + l15) * XP_ + kc * 32 + quad * 8]);
        acc[m] = __builtin_amdgcn_mfma_f32_16x16x32_bf16(afr, bfr, acc[m], 0, 0, 0);
      }
    }
    float* ob = out + (size_t)b * C_ * N_ + gp0 + n0 + l15;
#pragma unroll
    for (int m = 0; m < 6; ++m) {
      const int chb = m * 16 + quad * 4;
#pragma unroll
      for (int r = 0; r < 4; ++r)
        ob[(size_t)(chb + r) * N_] = acc[m][r] + Bl[chb + r];
    }
  }
}

extern "C" void kernel_launch(void* const* d_in, const int* in_sizes, int n_in,
                              void* d_out, int out_size, void* d_ws, size_t ws_size,
                              hipStream_t stream) {
  const float* x      = (const float*)d_in[0];
  const float* qkv_w  = (const float*)d_in[1];
  const float* qkv_b  = (const float*)d_in[2];
  const float* dw_w   = (const float*)d_in[3];
  const float* dw_b   = (const float*)d_in[4];
  const float* proj_w = (const float*)d_in[5];
  const float* proj_b = (const float*)d_in[6];

  float* out      = (float*)d_out;                       // [4,96,256,256]
  float* attn_out = out + (size_t)B_ * C_ * N_;          // [4,3,32,32]

  unsigned short* A = (unsigned short*)d_ws;             // 151 MB bf16
  float* inv   = (float*)(A + (size_t)B_ * C3_ * N_);
  float* araw  = inv + 768;
  unsigned short* wq_bf = (unsigned short*)(araw + 12288);
  unsigned short* wp_bf = wq_bf + C3_ * C_;

  k_cast<<<108, 256, 0, stream>>>(qkv_w, wq_bf, C3_ * C_);
  k_cast<<<36, 256, 0, stream>>>(proj_w, wp_bf, C_ * C_);
  k1_mfma<<<dim3(512, B_), 256, 0, stream>>>(x, wq_bf, qkv_b, A);
  k_dw_reg<<<B_ * C3_, 256, 0, stream>>>(A, dw_w, dw_b, inv);
  k_zero<<<48, 256, 0, stream>>>(araw, HEAD_ * B_ * 1024);
  k_attn_partial<<<dim3(16, HEAD_, B_), 256, 0, stream>>>(A, araw);
  k_softmax<<<48, 256, 0, stream>>>(araw, inv, attn_out);
  k_attn_v<<<dim3(N_ / 256, HEAD_, B_), 256, 0, stream>>>(A, attn_out, A);
  k7_mfma<<<dim3(256, B_), 256, 0, stream>>>(A, wp_bf, proj_b, out);
}

// Round 5
// 382.013 us; speedup vs baseline: 2.2826x; 1.2414x over previous
//
#include <hip/hip_runtime.h>
#include <hip/hip_bf16.h>

// Problem dims (StandardAttention): x[4,96,256,256], heads=3
#define B_  4
#define C_  96
#define H_  256
#define W_  256
#define N_  (H_*W_)      // 65536
#define C3_ 288
#define HEAD_ 3
#define HC_ 32
#define EPS_ 1e-12f
#define XP_ 104          // padded LDS row stride (ushorts): word-stride 52 -> conflict-free b128
#define SPLITS_ 128      // split-K segments for QK^T

typedef __attribute__((ext_vector_type(8))) short short8;
typedef __attribute__((ext_vector_type(4))) float f32x4;

// ---- bf16 helpers (raw ushort storage) -------------------------------------
__device__ __forceinline__ unsigned short f2bf(float f) {
  unsigned u = __float_as_uint(f);
  u += 0x7fffu + ((u >> 16) & 1u);      // round-to-nearest-even
  return (unsigned short)(u >> 16);
}
__device__ __forceinline__ float bf2f(unsigned short h) {
  return __uint_as_float((unsigned)h << 16);
}
__device__ __forceinline__ float bf_lo(unsigned u) { return __uint_as_float(u << 16); }
__device__ __forceinline__ float bf_hi(unsigned u) { return __uint_as_float(u & 0xffff0000u); }
__device__ __forceinline__ unsigned pack_bf(float a, float b) {
  return (unsigned)f2bf(a) | ((unsigned)f2bf(b) << 16);
}

// ---------------- K0: fp32 -> bf16 cast (for weights) -----------------------
__global__ __launch_bounds__(256) void k_cast(
    const float* __restrict__ s, unsigned short* __restrict__ d, int n) {
  const int i = blockIdx.x * 256 + threadIdx.x;
  if (i < n) d[i] = f2bf(s[i]);
}

// ---------------- K1: qkv = qkv_w @ x + qkv_b  via MFMA ---------------------
__global__ __launch_bounds__(256) void k1_mfma(
    const float* __restrict__ x, const unsigned short* __restrict__ wbf,
    const float* __restrict__ bias, unsigned short* __restrict__ out) {
  __shared__ unsigned short Wl[C3_ * XP_];    // 59904 B, [ch][k] stride 104
  __shared__ unsigned short Xt[32 * XP_];     // 6656 B,  [pix][k] stride 104
  __shared__ float Bl[C3_];
  const int tid = threadIdx.x;
  const int b = blockIdx.y;
  for (int i = tid; i < C3_ * C_; i += 256) {
    const int c = i / 96, k = i % 96;
    Wl[c * XP_ + k] = wbf[i];
  }
  for (int i = tid; i < C3_; i += 256) Bl[i] = bias[i];
  const int lane = tid & 63;
  const int wv = tid >> 6;             // 0..3
  const int n0 = (wv & 1) * 16;        // pixel subgroup base
  const int mbase = (wv >> 1) * 144;   // 9 M-tiles of 16 channels
  const int l15 = lane & 15, quad = lane >> 4;
  for (int ti = blockIdx.x; ti < N_ / 32; ti += gridDim.x) {
    const int gp0 = ti * 32;
    __syncthreads();
    const float* xb = x + ((size_t)b * C_) * N_ + gp0;
#pragma unroll
    for (int l = 0; l < 12; ++l) {
      const int idx = tid + l * 256;
      const int c = idx >> 5, p = idx & 31;
      Xt[p * XP_ + c] = f2bf(xb[(size_t)c * N_ + p]);
    }
    __syncthreads();
    f32x4 acc[9];
#pragma unroll
    for (int m = 0; m < 9; ++m) acc[m] = (f32x4){0.f, 0.f, 0.f, 0.f};
#pragma unroll
    for (int kc = 0; kc < 3; ++kc) {
      const short8 bfr = *reinterpret_cast<const short8*>(&Xt[(n0 + l15) * XP_ + kc * 32 + quad * 8]);
#pragma unroll
      for (int m = 0; m < 9; ++m) {
        const short8 afr = *reinterpret_cast<const short8*>(
            &Wl[(mbase + m * 16 + l15) * XP_ + kc * 32 + quad * 8]);
        acc[m] = __builtin_amdgcn_mfma_f32_16x16x32_bf16(afr, bfr, acc[m], 0, 0, 0);
      }
    }
    unsigned short* ob = out + (size_t)b * C3_ * N_ + gp0 + n0 + l15;
#pragma unroll
    for (int m = 0; m < 9; ++m) {
      const int chb = mbase + m * 16 + quad * 4;
#pragma unroll
      for (int r = 0; r < 4; ++r)
        ob[(size_t)(chb + r) * N_] = f2bf(acc[m][r] + Bl[chb + r]);
    }
  }
}

// ---------------- K2: 3x3 depthwise conv IN-PLACE, register-rolling ---------
__global__ __launch_bounds__(256) void k_dw_reg(
    unsigned short* a, const float* __restrict__ w9,
    const float* __restrict__ bias, float* __restrict__ inv) {
  const int bc = blockIdx.x;            // 0..1151
  const int ch = bc % C3_;
  unsigned short* p = a + (size_t)bc * N_;
  const int tid = threadIdx.x;
  const int tr = tid >> 5;              // 0..7 row segment
  const int tc = tid & 31;
  const int x0 = tc * 8;
  const int y0 = tr * 32;
  float wv[9];
#pragma unroll
  for (int i = 0; i < 9; ++i) wv[i] = w9[ch * 9 + i];
  const float bv = bias[ch];

  auto load_row = [&](int y, float* d) {
    if ((unsigned)y >= 256u) {
#pragma unroll
      for (int j = 0; j < 10; ++j) d[j] = 0.f;
      return;
    }
    const unsigned short* rp = p + (size_t)y * W_;
    const uint4 u = *reinterpret_cast<const uint4*>(rp + x0);
    d[1] = bf_lo(u.x); d[2] = bf_hi(u.x); d[3] = bf_lo(u.y); d[4] = bf_hi(u.y);
    d[5] = bf_lo(u.z); d[6] = bf_hi(u.z); d[7] = bf_lo(u.w); d[8] = bf_hi(u.w);
    d[0] = (tc > 0) ? bf2f(rp[x0 - 1]) : 0.f;
    d[9] = (tc < 31) ? bf2f(rp[x0 + 8]) : 0.f;
  };

  float rm[10], rc[10], rn[10], rb[10];
  load_row(y0 - 1, rm);
  load_row(y0, rc);
  load_row(y0 + 1, rn);
  load_row(y0 + 32, rb);     // bottom boundary: original data, pre-barrier
  __syncthreads();           // all preloads done before any write

  float ss = 0.f;
  for (int y = y0; y < y0 + 32; ++y) {
    float o[8];
#pragma unroll
    for (int j = 0; j < 8; ++j) {
      o[j] = bv + wv[0] * rm[j] + wv[1] * rm[j + 1] + wv[2] * rm[j + 2]
                + wv[3] * rc[j] + wv[4] * rc[j + 1] + wv[5] * rc[j + 2]
                + wv[6] * rn[j] + wv[7] * rn[j + 1] + wv[8] * rn[j + 2];
      ss += o[j] * o[j];
    }
    uint4 st;
    st.x = pack_bf(o[0], o[1]); st.y = pack_bf(o[2], o[3]);
    st.z = pack_bf(o[4], o[5]); st.w = pack_bf(o[6], o[7]);
    *reinterpret_cast<uint4*>(p + (size_t)y * W_ + x0) = st;
#pragma unroll
    for (int j = 0; j < 10; ++j) { rm[j] = rc[j]; rc[j] = rn[j]; }
    const int ny = y + 2;
    if (ny <= y0 + 31) {
      load_row(ny, rn);
    } else if (ny == y0 + 32) {
#pragma unroll
      for (int j = 0; j < 10; ++j) rn[j] = rb[j];
    }
  }
#pragma unroll
  for (int off = 32; off > 0; off >>= 1) ss += __shfl_down(ss, off, 64);
  __shared__ float red[4];
  if ((tid & 63) == 0) red[tid >> 6] = ss;
  __syncthreads();
  if (tid == 0 && ch < 192) {
    const float t = red[0] + red[1] + red[2] + red[3];
    const int b = bc / C3_;
    inv[b * 192 + ch] = 1.0f / fmaxf(sqrtf(t), EPS_);
  }
}

// ---------------- K4: QK^T via MFMA, split-K partials (no atomics) ----------
// Block = 4 waves = the four 16x16 tiles of the 32x32 gram. Fragments are
// contiguous 16B global loads (no LDS). part[seg][bh][32][32].
__global__ __launch_bounds__(256) void k_attn_mfma(
    const unsigned short* __restrict__ dw, float* __restrict__ part) {
  const int tid = threadIdx.x;
  const int lane = tid & 63;
  const int wv = tid >> 6;
  const int i0 = (wv >> 1) * 16, j0 = (wv & 1) * 16;
  const int h = blockIdx.y, b = blockIdx.z;
  const int n0 = blockIdx.x * (N_ / SPLITS_);    // 512-px segment
  const int l15 = lane & 15, quad = lane >> 4;
  const unsigned short* qrow =
      dw + ((size_t)(b * C3_ + h * HC_ + i0 + l15)) * N_ + n0 + quad * 8;
  const unsigned short* krow =
      dw + ((size_t)(b * C3_ + C_ + h * HC_ + j0 + l15)) * N_ + n0 + quad * 8;
  f32x4 acc = (f32x4){0.f, 0.f, 0.f, 0.f};
#pragma unroll 4
  for (int s = 0; s < N_ / SPLITS_; s += 32) {
    const short8 af = *reinterpret_cast<const short8*>(qrow + s);
    const short8 bf = *reinterpret_cast<const short8*>(krow + s);
    acc = __builtin_amdgcn_mfma_f32_16x16x32_bf16(af, bf, acc, 0, 0, 0);
  }
  // C layout: col=lane&15 -> j, row=quad*4+r -> i
  float* pp = part + (size_t)blockIdx.x * (B_ * HEAD_ * 1024)
                   + ((size_t)(b * HEAD_ + h)) * 1024;
#pragma unroll
  for (int r = 0; r < 4; ++r)
    pp[(i0 + quad * 4 + r) * 32 + j0 + l15] = acc[r];
}

// ---------------- K5: reduce partials, scale by inv norms, softmax ----------
__global__ __launch_bounds__(256) void k_softmax(
    const float* __restrict__ part, const float* __restrict__ inv,
    float* __restrict__ attn_out) {
  const int tid = threadIdx.x;
  const int R = blockIdx.x * 8 + (tid >> 5);   // 0..383 = (b*3+h)*32+i
  const int j = tid & 31;
  const int b = R / 96, rem = R % 96;
  const int h = rem / 32, i = rem % 32;
  float v = 0.f;
  for (int s = 0; s < SPLITS_; ++s)
    v += part[(size_t)s * (B_ * HEAD_ * 1024) + R * 32 + j];
  const float invq = inv[b * 192 + h * 32 + i];
  const float invk = inv[b * 192 + 96 + h * 32 + j];
  v *= invq * invk;                             // TEMP = 1
  float m = v;
#pragma unroll
  for (int off = 16; off > 0; off >>= 1) m = fmaxf(m, __shfl_xor(m, off, 32));
  const float e = __expf(v - m);
  float s = e;
#pragma unroll
  for (int off = 16; off > 0; off >>= 1) s += __shfl_xor(s, off, 32);
  attn_out[R * 32 + j] = e / s;
}

// ---------------- K6: out_mid (bf16, into A's q-region), 2 px/thread --------
__global__ __launch_bounds__(256) void k_attn_v(
    const unsigned short* __restrict__ dwv, const float* __restrict__ attn,
    unsigned short* __restrict__ out_mid) {
  __shared__ float as_[1024];
  const int tid = threadIdx.x;
  const int h = blockIdx.y, b = blockIdx.z;
  const int n = (blockIdx.x * 256 + tid) * 2;
  const float* ap = attn + ((size_t)(b * HEAD_ + h)) * 1024;
  for (int l = tid; l < 1024; l += 256) as_[l] = ap[l];
  __syncthreads();
  const unsigned short* vp = dwv + ((size_t)(b * C3_ + 2 * C_ + h * HC_)) * N_ + n;
  float a0[32], a1[32];
#pragma unroll
  for (int i = 0; i < 32; ++i) { a0[i] = 0.f; a1[i] = 0.f; }
#pragma unroll
  for (int j = 0; j < 32; ++j) {
    const unsigned u = *reinterpret_cast<const unsigned*>(vp + (size_t)j * N_);
    const float v0 = bf_lo(u), v1 = bf_hi(u);
#pragma unroll
    for (int i = 0; i < 32; ++i) {
      const float w = as_[i * 32 + j];
      a0[i] += w * v0; a1[i] += w * v1;
    }
  }
  unsigned short* op = out_mid + ((size_t)(b * C3_) + h * HC_) * N_ + n;
#pragma unroll
  for (int i = 0; i < 32; ++i)
    *reinterpret_cast<unsigned*>(op + (size_t)i * N_) = pack_bf(a0[i], a1[i]);
}

// ---------------- K7: out = proj_w @ out_mid + proj_b via MFMA --------------
__global__ __launch_bounds__(256) void k7_mfma(
    const unsigned short* __restrict__ mid,
    const unsigned short* __restrict__ wbf,
    const float* __restrict__ bias, float* __restrict__ out) {
  __shared__ unsigned short Wl[C_ * XP_];     // 19968 B
  __shared__ unsigned short Xt[64 * XP_];     // 13312 B
  __shared__ float Bl[C_];
  const int tid = threadIdx.x;
  const int b = blockIdx.y;
  for (int i = tid; i < C_ * C_; i += 256) {
    const int c = i / 96, k = i % 96;
    Wl[c * XP_ + k] = wbf[i];
  }
  if (tid < C_) Bl[tid] = bias[tid];
  const int lane = tid & 63;
  const int wv = tid >> 6;
  const int n0 = wv * 16;
  const int l15 = lane & 15, quad = lane >> 4;
  for (int ti = blockIdx.x; ti < N_ / 64; ti += gridDim.x) {
    const int gp0 = ti * 64;
    __syncthreads();
    const unsigned short* xb = mid + (size_t)b * C3_ * N_ + gp0;
#pragma unroll
    for (int l = 0; l < 24; ++l) {
      const int idx = tid + l * 256;
      const int c = idx >> 6, p = idx & 63;
      Xt[p * XP_ + c] = xb[(size_t)c * N_ + p];
    }
    __syncthreads();
    f32x4 acc[6];
#pragma unroll
    for (int m = 0; m < 6; ++m) acc[m] = (f32x4){0.f, 0.f, 0.f, 0.f};
#pragma unroll
    for (int kc = 0; kc < 3; ++kc) {
      const short8 bfr = *reinterpret_cast<const short8*>(&Xt[(n0 + l15) * XP_ + kc * 32 + quad * 8]);
#pragma unroll
      for (int m = 0; m < 6; ++m) {
        const short8 afr = *reinterpret_cast<const short8*>(
            &Wl[(m * 16 + l15) * XP_ + kc * 32 + quad * 8]);
        acc[m] = __builtin_amdgcn_mfma_f32_16x16x32_bf16(afr, bfr, acc[m], 0, 0, 0);
      }
    }
    float* ob = out + (size_t)b * C_ * N_ + gp0 + n0 + l15;
#pragma unroll
    for (int m = 0; m < 6; ++m) {
      const int chb = m * 16 + quad * 4;
#pragma unroll
      for (int r = 0; r < 4; ++r)
        ob[(size_t)(chb + r) * N_] = acc[m][r] + Bl[chb + r];
    }
  }
}

extern "C" void kernel_launch(void* const* d_in, const int* in_sizes, int n_in,
                              void* d_out, int out_size, void* d_ws, size_t ws_size,
                              hipStream_t stream) {
  const float* x      = (const float*)d_in[0];
  const float* qkv_w  = (const float*)d_in[1];
  const float* qkv_b  = (const float*)d_in[2];
  const float* dw_w   = (const float*)d_in[3];
  const float* dw_b   = (const float*)d_in[4];
  const float* proj_w = (const float*)d_in[5];
  const float* proj_b = (const float*)d_in[6];

  float* out      = (float*)d_out;                       // [4,96,256,256]
  float* attn_out = out + (size_t)B_ * C_ * N_;          // [4,3,32,32]

  unsigned short* A = (unsigned short*)d_ws;             // 151 MB bf16
  float* inv   = (float*)(A + (size_t)B_ * C3_ * N_);
  float* part  = inv + 768;                              // 128*12288 fp32 = 6.3 MB
  unsigned short* wq_bf = (unsigned short*)(part + SPLITS_ * B_ * HEAD_ * 1024);
  unsigned short* wp_bf = wq_bf + C3_ * C_;

  k_cast<<<108, 256, 0, stream>>>(qkv_w, wq_bf, C3_ * C_);
  k_cast<<<36, 256, 0, stream>>>(proj_w, wp_bf, C_ * C_);
  k1_mfma<<<dim3(512, B_), 256, 0, stream>>>(x, wq_bf, qkv_b, A);
  k_dw_reg<<<B_ * C3_, 256, 0, stream>>>(A, dw_w, dw_b, inv);
  k_attn_mfma<<<dim3(SPLITS_, HEAD_, B_), 256, 0, stream>>>(A, part);
  k_softmax<<<48, 256, 0, stream>>>(part, inv, attn_out);
  k_attn_v<<<dim3(N_ / 512, HEAD_, B_), 256, 0, stream>>>(A, attn_out, A);
  k7_mfma<<<dim3(256, B_), 256, 0, stream>>>(A, wp_bf, proj_b, out);
}